// Round 3
// baseline (338.712 us; speedup 1.0000x reference)
//
#include <hip/hip_runtime.h>

// Shapes: B=1, S=128, Q=256, C=256, H=8, DH=32, TOT=256. Inputs/out f32.
// Intermediates bf16. NOTE: numerics must stay bit-identical to R2
// (absmax 0.01953125 vs threshold 0.019609): RNE conversions, ascending-k
// MFMA accumulation, identical softmax op order.

typedef unsigned short u16;
typedef unsigned int   u32;
typedef float  f32x4  __attribute__((ext_vector_type(4)));
typedef __bf16 bf16x8 __attribute__((ext_vector_type(8)));
typedef u16    u16x4  __attribute__((ext_vector_type(4)));

__device__ __forceinline__ float bf2f(u16 u) {
    union { u32 i; float f; } v; v.i = ((u32)u) << 16; return v.f;
}
// RNE f32->bf16 (hardware cvt; identical to add-0x7FFF software RNE on normals)
__device__ __forceinline__ u16 f2bf(float f) {
    __bf16 h = (__bf16)f; return __builtin_bit_cast(u16, h);
}

// -------------------------------------------------------------------------
// Pass 1: qx, kvx f32 -> bf16 (Xq, Xkv live in d_out scratch; exact fit)
// -------------------------------------------------------------------------
__global__ __launch_bounds__(256) void cvt2bf(
    const float4* __restrict__ qx, const float4* __restrict__ kvx,
    u16* __restrict__ Xq, u16* __restrict__ Xkv)
{
    const int g0 = blockIdx.x * 256 + threadIdx.x;
    #pragma unroll
    for (int it = 0; it < 4; ++it) {
        const int g = g0 + it * 1048576;           // 4,194,304 float4 total
        const bool first = g < 2097152;
        float4 v = first ? qx[g] : kvx[g - 2097152];
        u16* d = first ? (Xq + (size_t)g * 4) : (Xkv + (size_t)(g - 2097152) * 4);
        u16x4 r; r.x = f2bf(v.x); r.y = f2bf(v.y); r.z = f2bf(v.z); r.w = f2bf(v.w);
        *(u16x4*)d = r;
    }
}

// -------------------------------------------------------------------------
// LDS-free GEMM core: C[m,n] = act( sum_k A[m,k]*W[n,k] + bias[n] ).
// A bf16 [.,256], W f32 [.,256]. 128x128 block tile, 4 waves 2x2, wave 64x64.
// Fragments loaded straight from global (A: bf16x8; W: 2x float4 + RNE cvt).
// K ascending, fully unrolled -> bit-identical accumulation to R2.
// -------------------------------------------------------------------------
__device__ __forceinline__ void store_out(float* p, float v) { *p = v; }
__device__ __forceinline__ void store_out(u16*   p, float v) { *p = f2bf(v); }

template <typename TO>
__device__ __forceinline__ void gemm_core(
    const u16* __restrict__ A, const float* __restrict__ W,
    const float* __restrict__ bias, TO* __restrict__ out, int act,
    int m0, int n0, int tid)
{
    const int lane = tid & 63;
    const int w    = tid >> 6;
    const int quad = lane >> 4;
    const int ln   = lane & 15;
    const int wm   = (w >> 1) * 64;
    const int wn   = (w & 1) * 64;

    f32x4 acc[4][4] = {};

    #pragma unroll
    for (int kk = 0; kk < 8; ++kk) {
        const int k0 = kk * 32;
        bf16x8 af[4], bfr[4];
        #pragma unroll
        for (int i = 0; i < 4; ++i)
            af[i] = __builtin_bit_cast(bf16x8,
                *(const uint4*)(A + (size_t)(m0 + wm + i * 16 + ln) * 256 + k0 + quad * 8));
        #pragma unroll
        for (int j = 0; j < 4; ++j) {
            const float4* wp = (const float4*)(W + (size_t)(n0 + wn + j * 16 + ln) * 256 + k0 + quad * 8);
            float4 x = wp[0], y = wp[1];
            bf16x8 b;
            b[0] = (__bf16)x.x; b[1] = (__bf16)x.y; b[2] = (__bf16)x.z; b[3] = (__bf16)x.w;
            b[4] = (__bf16)y.x; b[5] = (__bf16)y.y; b[6] = (__bf16)y.z; b[7] = (__bf16)y.w;
            bfr[j] = b;
        }
        #pragma unroll
        for (int i = 0; i < 4; ++i)
            #pragma unroll
            for (int j = 0; j < 4; ++j)
                acc[i][j] = __builtin_amdgcn_mfma_f32_16x16x32_bf16(af[i], bfr[j], acc[i][j], 0, 0, 0);
    }

    #pragma unroll
    for (int i = 0; i < 4; ++i) {
        #pragma unroll
        for (int j = 0; j < 4; ++j) {
            #pragma unroll
            for (int rr = 0; rr < 4; ++rr) {
                const int row = m0 + wm + i * 16 + quad * 4 + rr;  // C/D: row=quad*4+reg
                const int col = n0 + wn + j * 16 + ln;             //      col=lane&15
                float v = acc[i][j][rr];
                if (bias) v += bias[col];
                if (act)  v = 1.0f / (1.0f + __expf(-v));
                store_out(&out[(size_t)row * 256 + col], v);
            }
        }
    }
}

// Pass 2: fused Q/K/V/G projections. bid = m0-major, nb = bid&7 fastest so
// the 8 sibling blocks sharing an A tile are dispatched adjacently.
__global__ __launch_bounds__(256, 2) void proj_all(
    const u16* __restrict__ Xq, const u16* __restrict__ Xkv,
    const float* __restrict__ Wq, const float* __restrict__ Wk,
    const float* __restrict__ Wv, const float* __restrict__ Wg,
    const float* __restrict__ bg,
    u16* __restrict__ Qb, u16* __restrict__ Kb, u16* __restrict__ Vb, u16* __restrict__ Gb)
{
    const int bid = blockIdx.x;
    const int nb  = bid & 7;
    const int t   = nb >> 1;               // 0=Q 1=K 2=V 3=G
    const int n0  = (nb & 1) * 128;
    const int m0  = (bid >> 3) * 128;
    const u16*   A = (t == 0 || t == 3) ? Xq : Xkv;
    const float* W = (t == 0) ? Wq : (t == 1) ? Wk : (t == 2) ? Wv : Wg;
    u16*         O = (t == 0) ? Qb : (t == 1) ? Kb : (t == 2) ? Vb : Gb;
    gemm_core<u16>(A, W, (t == 3) ? bg : (const float*)nullptr, O, t == 3, m0, n0, threadIdx.x);
}

// Pass 4: output projection (+bo) to f32.
__global__ __launch_bounds__(256, 2) void gemm_out(
    const u16* __restrict__ Ob, const float* __restrict__ Wo,
    const float* __restrict__ bo, float* __restrict__ out)
{
    const int bid = blockIdx.x;
    gemm_core<float>(Ob, Wo, bo, out, 0, (bid >> 1) * 128, (bid & 1) * 128, threadIdx.x);
}

// -------------------------------------------------------------------------
// Pass 3: attention. Block = (h, s); 4 waves; wave w covers q in
// [w*64, w*64+64) as 4 m-tiles of 16. V^T + bias_mask staged once per block.
// Per-element math identical to R2 (bit-exact).
// -------------------------------------------------------------------------
__global__ __launch_bounds__(256) void attn_kernel(
    const u16* __restrict__ Qb, const u16* __restrict__ Kb, const u16* __restrict__ Vb,
    const u16* __restrict__ Gb, const float* __restrict__ bm, const float* __restrict__ bp,
    u16* __restrict__ Ob)
{
    __shared__ u16   Vt[32][264];       // V transposed: Vt[dh][kp]
    __shared__ u16   Pl[4][16][268];    // per-wave P tile (stride 268: quads on distinct banks)
    __shared__ float bmf[256];

    const int h    = blockIdx.x;
    const int s    = blockIdx.y;
    const int tid  = threadIdx.x;
    const int lane = tid & 63;
    const int w    = tid >> 6;
    const int quad = lane >> 4;
    const int ln   = lane & 15;

    {   // stage V^T (thread tid = key row) + bias_mask
        const uint4* vp = (const uint4*)(Vb + (size_t)(s * 256 + tid) * 256 + h * 32);
        uint4 vv0 = vp[0], vv1 = vp[1], vv2 = vp[2], vv3 = vp[3];
        u16 tmp[32];
        *(uint4*)&tmp[0]  = vv0; *(uint4*)&tmp[8]  = vv1;
        *(uint4*)&tmp[16] = vv2; *(uint4*)&tmp[24] = vv3;
        #pragma unroll
        for (int dh = 0; dh < 32; ++dh) Vt[dh][tid] = tmp[dh];
        bmf[tid] = bm[s * 256 + tid];
    }
    __syncthreads();

    for (int mt = 0; mt < 4; ++mt) {
        const int q0 = w * 64 + mt * 16;

        bf16x8 aq = __builtin_bit_cast(bf16x8,
            *(const uint4*)(Qb + (size_t)(s * 256 + q0 + ln) * 256 + h * 32 + quad * 8));

        f32x4 sc[16];
        #pragma unroll
        for (int nt = 0; nt < 16; ++nt) {
            bf16x8 bk = __builtin_bit_cast(bf16x8,
                *(const uint4*)(Kb + (size_t)(s * 256 + nt * 16 + ln) * 256 + h * 32 + quad * 8));
            f32x4 z = {0.f, 0.f, 0.f, 0.f};
            sc[nt] = __builtin_amdgcn_mfma_f32_16x16x32_bf16(aq, bk, z, 0, 0, 0);
        }

        float rmax[4] = {-1e30f, -1e30f, -1e30f, -1e30f};
        #pragma unroll
        for (int nt = 0; nt < 16; ++nt) {
            const int kp = nt * 16 + ln;
            const float bmv = bmf[kp];
            #pragma unroll
            for (int rr = 0; rr < 4; ++rr) {
                const int q = q0 + quad * 4 + rr;
                float v = sc[nt][rr] + bmv + bp[(size_t)(h * 256 + q) * 256 + kp];
                sc[nt][rr] = v;
                rmax[rr] = fmaxf(rmax[rr], v);
            }
        }
        #pragma unroll
        for (int rr = 0; rr < 4; ++rr) {
            float m = rmax[rr];
            m = fmaxf(m, __shfl_xor(m, 1));
            m = fmaxf(m, __shfl_xor(m, 2));
            m = fmaxf(m, __shfl_xor(m, 4));
            m = fmaxf(m, __shfl_xor(m, 8));
            rmax[rr] = m;
        }
        float rsum[4] = {0.f, 0.f, 0.f, 0.f};
        #pragma unroll
        for (int nt = 0; nt < 16; ++nt)
            #pragma unroll
            for (int rr = 0; rr < 4; ++rr) {
                float p = __expf(sc[nt][rr] - rmax[rr]);
                sc[nt][rr] = p;
                rsum[rr] += p;
            }
        float rinv[4];
        #pragma unroll
        for (int rr = 0; rr < 4; ++rr) {
            float t = rsum[rr];
            t += __shfl_xor(t, 1);
            t += __shfl_xor(t, 2);
            t += __shfl_xor(t, 4);
            t += __shfl_xor(t, 8);
            rinv[rr] = 1.0f / t;
        }

        #pragma unroll
        for (int nt = 0; nt < 16; ++nt)
            #pragma unroll
            for (int rr = 0; rr < 4; ++rr)
                Pl[w][quad * 4 + rr][nt * 16 + ln] = f2bf(sc[nt][rr] * rinv[rr]);

        f32x4 o0 = {0.f, 0.f, 0.f, 0.f}, o1 = {0.f, 0.f, 0.f, 0.f};
        #pragma unroll
        for (int kc = 0; kc < 8; ++kc) {
            bf16x8 pa = __builtin_bit_cast(bf16x8, *(const uint4*)&Pl[w][ln][kc * 32 + quad * 8]);
            bf16x8 v0 = __builtin_bit_cast(bf16x8, *(const uint4*)&Vt[ln][kc * 32 + quad * 8]);
            bf16x8 v1 = __builtin_bit_cast(bf16x8, *(const uint4*)&Vt[16 + ln][kc * 32 + quad * 8]);
            o0 = __builtin_amdgcn_mfma_f32_16x16x32_bf16(pa, v0, o0, 0, 0, 0);
            o1 = __builtin_amdgcn_mfma_f32_16x16x32_bf16(pa, v1, o1, 0, 0, 0);
        }

        #pragma unroll
        for (int rr = 0; rr < 4; ++rr) {
            const int q = q0 + quad * 4 + rr;
            const size_t base = (size_t)(s * 256 + q) * 256 + h * 32;
            float g0 = bf2f(Gb[base + ln]);
            float g1 = bf2f(Gb[base + 16 + ln]);
            Ob[base + ln]      = f2bf(o0[rr] * g0);
            Ob[base + 16 + ln] = f2bf(o1[rr] * g1);
        }
    }
}

// -------------------------------------------------------------------------
extern "C" void kernel_launch(void* const* d_in, const int* in_sizes, int n_in,
                              void* d_out, int out_size, void* d_ws, size_t ws_size,
                              hipStream_t stream)
{
    const float* qx  = (const float*)d_in[0];
    const float* kvx = (const float*)d_in[1];
    const float* bm  = (const float*)d_in[2];
    const float* bp  = (const float*)d_in[3];
    const float* Wq  = (const float*)d_in[4];
    const float* Wk  = (const float*)d_in[5];
    const float* Wv  = (const float*)d_in[6];
    const float* Wg  = (const float*)d_in[7];
    const float* bg  = (const float*)d_in[8];
    const float* Wo  = (const float*)d_in[9];
    const float* bo  = (const float*)d_in[10];
    float* out = (float*)d_out;

    // ws: 5 bf16 buffers of 32768x256 = 83.9 MB (proven size from R2)
    const size_t NEL = (size_t)32768 * 256;
    u16* Qb = (u16*)d_ws;
    u16* Kb = Qb + NEL;
    u16* Vb = Kb + NEL;
    u16* Gb = Vb + NEL;
    u16* Ob = Gb + NEL;

    // d_out doubles as scratch for bf16 copies of qx/kvx (exact 33.55 MB fit);
    // it is fully overwritten by gemm_out at the end.
    u16* Xq  = (u16*)d_out;
    u16* Xkv = Xq + NEL;

    cvt2bf<<<dim3(4096), dim3(256), 0, stream>>>((const float4*)qx, (const float4*)kvx, Xq, Xkv);

    proj_all<<<dim3(2048), dim3(256), 0, stream>>>(Xq, Xkv, Wq, Wk, Wv, Wg, bg, Qb, Kb, Vb, Gb);

    attn_kernel<<<dim3(8, 128), dim3(256), 0, stream>>>(Qb, Kb, Vb, Gb, bm, bp, Ob);

    gemm_out<<<dim3(512), dim3(256), 0, stream>>>(Ob, Wo, bo, out);
}

// Round 4
// 264.728 us; speedup vs baseline: 1.2795x; 1.2795x over previous
//
#include <hip/hip_runtime.h>

// Shapes: B=1, S=128, Q=256, C=256, H=8, DH=32, TOT=256. Inputs/out f32.
// Intermediates bf16 in d_ws. Numerics bit-identical to R2/R3 (absmax
// 0.01953125 vs thr 0.019609): RNE cvt, ascending-k MFMA accumulation,
// identical softmax op order.

typedef unsigned short u16;
typedef unsigned int   u32;
typedef float  f32x4  __attribute__((ext_vector_type(4)));
typedef __bf16 bf16x8 __attribute__((ext_vector_type(8)));

__device__ __forceinline__ float bf2f(u16 u) {
    union { u32 i; float f; } v; v.i = ((u32)u) << 16; return v.f;
}
__device__ __forceinline__ u16 f2bf(float f) {      // hw RNE cvt
    __bf16 h = (__bf16)f; return __builtin_bit_cast(u16, h);
}

// ---- staging: 16 contiguous elems -> bf16 regs ----
__device__ __forceinline__ void load16_bf16(const float* src, u16* dst) {
    const float4* p = (const float4*)src;
    float4 f0 = p[0], f1 = p[1], f2 = p[2], f3 = p[3];
    dst[0]  = f2bf(f0.x); dst[1]  = f2bf(f0.y); dst[2]  = f2bf(f0.z); dst[3]  = f2bf(f0.w);
    dst[4]  = f2bf(f1.x); dst[5]  = f2bf(f1.y); dst[6]  = f2bf(f1.z); dst[7]  = f2bf(f1.w);
    dst[8]  = f2bf(f2.x); dst[9]  = f2bf(f2.y); dst[10] = f2bf(f2.z); dst[11] = f2bf(f2.w);
    dst[12] = f2bf(f3.x); dst[13] = f2bf(f3.y); dst[14] = f2bf(f3.z); dst[15] = f2bf(f3.w);
}
__device__ __forceinline__ void load16_bf16(const u16* src, u16* dst) {
    const uint4* p = (const uint4*)src;
    uint4 a0 = p[0], a1 = p[1];
    *(uint4*)&dst[0] = a0; *(uint4*)&dst[8] = a1;
}
__device__ __forceinline__ void store_out(float* p, float v) { *p = v; }
__device__ __forceinline__ void store_out(u16*   p, float v) { *p = f2bf(v); }

// -------------------------------------------------------------------------
// LDS-staged GEMM core (R2-proven): C[m,n]=act(sum_k A[m,k]*W[n,k]+bias[n]).
// 128x128 block tile, 4 waves 2x2, wave 64x64 = 4x4 mfma_f32_16x16x32_bf16.
// -------------------------------------------------------------------------
template <typename TA, typename TO>
__device__ __forceinline__ void gemm_staged(
    const TA* __restrict__ A, const float* __restrict__ W,
    const float* __restrict__ bias, TO* __restrict__ out, int act,
    int m0, int n0, int tid)
{
    __shared__ u16 At[128][40];   // stride 40: worst 2-way bank alias (free, m136)
    __shared__ u16 Wt[128][40];

    const int lane = tid & 63;
    const int w    = tid >> 6;
    const int quad = lane >> 4;
    const int ln   = lane & 15;
    const int wm   = (w >> 1) * 64;
    const int wn   = (w & 1) * 64;

    f32x4 acc[4][4] = {};

    const int r  = tid >> 1;          // staging row 0..127
    const int c0 = (tid & 1) * 16;    // staging col 0 or 16

    for (int k0 = 0; k0 < 256; k0 += 32) {
        u16 ta[16], tw[16];
        load16_bf16(A + (size_t)(m0 + r) * 256 + k0 + c0, ta);
        load16_bf16(W + (size_t)(n0 + r) * 256 + k0 + c0, tw);
        __syncthreads();              // previous iter's LDS reads drained
        *(uint4*)&At[r][c0] = *(uint4*)&ta[0]; *(uint4*)&At[r][c0 + 8] = *(uint4*)&ta[8];
        *(uint4*)&Wt[r][c0] = *(uint4*)&tw[0]; *(uint4*)&Wt[r][c0 + 8] = *(uint4*)&tw[8];
        __syncthreads();

        bf16x8 af[4], bfr[4];
        #pragma unroll
        for (int i = 0; i < 4; ++i)
            af[i] = __builtin_bit_cast(bf16x8, *(const uint4*)&At[wm + i * 16 + ln][quad * 8]);
        #pragma unroll
        for (int j = 0; j < 4; ++j)
            bfr[j] = __builtin_bit_cast(bf16x8, *(const uint4*)&Wt[wn + j * 16 + ln][quad * 8]);
        #pragma unroll
        for (int i = 0; i < 4; ++i)
            #pragma unroll
            for (int j = 0; j < 4; ++j)
                acc[i][j] = __builtin_amdgcn_mfma_f32_16x16x32_bf16(af[i], bfr[j], acc[i][j], 0, 0, 0);
    }

    #pragma unroll
    for (int i = 0; i < 4; ++i) {
        #pragma unroll
        for (int j = 0; j < 4; ++j) {
            #pragma unroll
            for (int rr = 0; rr < 4; ++rr) {
                const int row = m0 + wm + i * 16 + quad * 4 + rr;  // C/D: row=quad*4+reg
                const int col = n0 + wn + j * 16 + ln;             //      col=lane&15
                float v = acc[i][j][rr];
                if (bias) v += bias[col];
                if (act)  v = 1.0f / (1.0f + __expf(-v));
                store_out(&out[(size_t)row * 256 + col], v);
            }
        }
    }
}

// Pass 1: fused Q/K/V/G projections. 2048 blocks (~6 resident/CU) so barrier
// stalls of one block overlap other blocks' MFMA (m114 wave-level overlap).
__global__ __launch_bounds__(256, 2) void proj_all(
    const float* __restrict__ qx, const float* __restrict__ kvx,
    const float* __restrict__ Wq, const float* __restrict__ Wk,
    const float* __restrict__ Wv, const float* __restrict__ Wg,
    const float* __restrict__ bg,
    u16* __restrict__ Qb, u16* __restrict__ Kb, u16* __restrict__ Vb, u16* __restrict__ Gb)
{
    const int bid = blockIdx.x;
    const int nb  = bid & 7;               // 8 siblings share the A m-tile -> L2-local
    const int t   = nb >> 1;               // 0=Q 1=K 2=V 3=G
    const int n0  = (nb & 1) * 128;
    const int m0  = (bid >> 3) * 128;
    const float* A = (t == 0 || t == 3) ? qx : kvx;
    const float* W = (t == 0) ? Wq : (t == 1) ? Wk : (t == 2) ? Wv : Wg;
    u16*         O = (t == 0) ? Qb : (t == 1) ? Kb : (t == 2) ? Vb : Gb;
    gemm_staged<float, u16>(A, W, (t == 3) ? bg : (const float*)nullptr, O, t == 3, m0, n0, threadIdx.x);
}

// Pass 3: output projection (+bo) to f32.
__global__ __launch_bounds__(256, 2) void gemm_out(
    const u16* __restrict__ Ob, const float* __restrict__ Wo,
    const float* __restrict__ bo, float* __restrict__ out)
{
    const int bid = blockIdx.x;
    gemm_staged<u16, float>(Ob, Wo, bo, out, 0, (bid >> 1) * 128, (bid & 1) * 128, threadIdx.x);
}

// -------------------------------------------------------------------------
// Pass 2: attention. Block = (h, s); 4 waves; wave w covers q [w*64, w*64+64)
// as 4 m-tiles of 16. V^T + bias_mask staged once; K re-reads hit L1.
// -------------------------------------------------------------------------
__global__ __launch_bounds__(256) void attn_kernel(
    const u16* __restrict__ Qb, const u16* __restrict__ Kb, const u16* __restrict__ Vb,
    const u16* __restrict__ Gb, const float* __restrict__ bm, const float* __restrict__ bp,
    u16* __restrict__ Ob)
{
    __shared__ u16   Vt[32][264];       // V transposed: Vt[dh][kp]
    __shared__ u16   Pl[4][16][268];    // per-wave P tile
    __shared__ float bmf[256];

    const int h    = blockIdx.x;
    const int s    = blockIdx.y;
    const int tid  = threadIdx.x;
    const int lane = tid & 63;
    const int w    = tid >> 6;
    const int quad = lane >> 4;
    const int ln   = lane & 15;

    {   // stage V^T (thread tid = key row) + bias_mask
        const uint4* vp = (const uint4*)(Vb + (size_t)(s * 256 + tid) * 256 + h * 32);
        uint4 vv0 = vp[0], vv1 = vp[1], vv2 = vp[2], vv3 = vp[3];
        u16 tmp[32];
        *(uint4*)&tmp[0]  = vv0; *(uint4*)&tmp[8]  = vv1;
        *(uint4*)&tmp[16] = vv2; *(uint4*)&tmp[24] = vv3;
        #pragma unroll
        for (int dh = 0; dh < 32; ++dh) Vt[dh][tid] = tmp[dh];
        bmf[tid] = bm[s * 256 + tid];
    }
    __syncthreads();

    for (int mt = 0; mt < 4; ++mt) {
        const int q0 = w * 64 + mt * 16;

        bf16x8 aq = __builtin_bit_cast(bf16x8,
            *(const uint4*)(Qb + (size_t)(s * 256 + q0 + ln) * 256 + h * 32 + quad * 8));

        f32x4 sc[16];
        #pragma unroll
        for (int nt = 0; nt < 16; ++nt) {
            bf16x8 bk = __builtin_bit_cast(bf16x8,
                *(const uint4*)(Kb + (size_t)(s * 256 + nt * 16 + ln) * 256 + h * 32 + quad * 8));
            f32x4 z = {0.f, 0.f, 0.f, 0.f};
            sc[nt] = __builtin_amdgcn_mfma_f32_16x16x32_bf16(aq, bk, z, 0, 0, 0);
        }

        float rmax[4] = {-1e30f, -1e30f, -1e30f, -1e30f};
        #pragma unroll
        for (int nt = 0; nt < 16; ++nt) {
            const int kp = nt * 16 + ln;
            const float bmv = bmf[kp];
            #pragma unroll
            for (int rr = 0; rr < 4; ++rr) {
                const int q = q0 + quad * 4 + rr;
                float v = sc[nt][rr] + bmv + bp[(size_t)(h * 256 + q) * 256 + kp];
                sc[nt][rr] = v;
                rmax[rr] = fmaxf(rmax[rr], v);
            }
        }
        #pragma unroll
        for (int rr = 0; rr < 4; ++rr) {
            float m = rmax[rr];
            m = fmaxf(m, __shfl_xor(m, 1));
            m = fmaxf(m, __shfl_xor(m, 2));
            m = fmaxf(m, __shfl_xor(m, 4));
            m = fmaxf(m, __shfl_xor(m, 8));
            rmax[rr] = m;
        }
        float rsum[4] = {0.f, 0.f, 0.f, 0.f};
        #pragma unroll
        for (int nt = 0; nt < 16; ++nt)
            #pragma unroll
            for (int rr = 0; rr < 4; ++rr) {
                float p = __expf(sc[nt][rr] - rmax[rr]);
                sc[nt][rr] = p;
                rsum[rr] += p;
            }
        float rinv[4];
        #pragma unroll
        for (int rr = 0; rr < 4; ++rr) {
            float t = rsum[rr];
            t += __shfl_xor(t, 1);
            t += __shfl_xor(t, 2);
            t += __shfl_xor(t, 4);
            t += __shfl_xor(t, 8);
            rinv[rr] = 1.0f / t;
        }

        #pragma unroll
        for (int nt = 0; nt < 16; ++nt)
            #pragma unroll
            for (int rr = 0; rr < 4; ++rr)
                Pl[w][quad * 4 + rr][nt * 16 + ln] = f2bf(sc[nt][rr] * rinv[rr]);

        f32x4 o0 = {0.f, 0.f, 0.f, 0.f}, o1 = {0.f, 0.f, 0.f, 0.f};
        #pragma unroll
        for (int kc = 0; kc < 8; ++kc) {
            bf16x8 pa = __builtin_bit_cast(bf16x8, *(const uint4*)&Pl[w][ln][kc * 32 + quad * 8]);
            bf16x8 v0 = __builtin_bit_cast(bf16x8, *(const uint4*)&Vt[ln][kc * 32 + quad * 8]);
            bf16x8 v1 = __builtin_bit_cast(bf16x8, *(const uint4*)&Vt[16 + ln][kc * 32 + quad * 8]);
            o0 = __builtin_amdgcn_mfma_f32_16x16x32_bf16(pa, v0, o0, 0, 0, 0);
            o1 = __builtin_amdgcn_mfma_f32_16x16x32_bf16(pa, v1, o1, 0, 0, 0);
        }

        #pragma unroll
        for (int rr = 0; rr < 4; ++rr) {
            const int q = q0 + quad * 4 + rr;
            const size_t base = (size_t)(s * 256 + q) * 256 + h * 32;
            float g0 = bf2f(Gb[base + ln]);
            float g1 = bf2f(Gb[base + 16 + ln]);
            Ob[base + ln]      = f2bf(o0[rr] * g0);
            Ob[base + 16 + ln] = f2bf(o1[rr] * g1);
        }
    }
}

// -------------------------------------------------------------------------
extern "C" void kernel_launch(void* const* d_in, const int* in_sizes, int n_in,
                              void* d_out, int out_size, void* d_ws, size_t ws_size,
                              hipStream_t stream)
{
    const float* qx  = (const float*)d_in[0];
    const float* kvx = (const float*)d_in[1];
    const float* bm  = (const float*)d_in[2];
    const float* bp  = (const float*)d_in[3];
    const float* Wq  = (const float*)d_in[4];
    const float* Wk  = (const float*)d_in[5];
    const float* Wv  = (const float*)d_in[6];
    const float* Wg  = (const float*)d_in[7];
    const float* bg  = (const float*)d_in[8];
    const float* Wo  = (const float*)d_in[9];
    const float* bo  = (const float*)d_in[10];
    float* out = (float*)d_out;

    // ws: 5 bf16 buffers of 32768x256 = 83.9 MB (proven in R2/R3)
    const size_t NEL = (size_t)32768 * 256;
    u16* Qb = (u16*)d_ws;
    u16* Kb = Qb + NEL;
    u16* Vb = Kb + NEL;
    u16* Gb = Vb + NEL;
    u16* Ob = Gb + NEL;

    proj_all<<<dim3(2048), dim3(256), 0, stream>>>(qx, kvx, Wq, Wk, Wv, Wg, bg, Qb, Kb, Vb, Gb);

    attn_kernel<<<dim3(8, 128), dim3(256), 0, stream>>>(Qb, Kb, Vb, Gb, bm, bp, Ob);

    gemm_out<<<dim3(512), dim3(256), 0, stream>>>(Ob, Wo, bo, out);
}